// Round 1
// baseline (10772.843 us; speedup 1.0000x reference)
//
#include <hip/hip_runtime.h>
#include <stdint.h>

#define B_  8
#define N_  256
#define DE_ 768
#define DH_ 192
#define L_  2
#define DC_ 192
#define G3  576     // 3*DH
#define G6  1152    // 6*DH
#define WRC 448     // padded Wrcat cols (385 -> 448, even pairs)

__device__ __forceinline__ float bf2f(uint32_t u) { return __uint_as_float(u << 16); }
__device__ __forceinline__ unsigned short f2bf(float f) {
    uint32_t x = __float_as_uint(f);
    x += 0x7fffu + ((x >> 16) & 1u);          // RNE
    return (unsigned short)(x >> 16);
}
__device__ __forceinline__ float sigm(float x)  { return 1.f / (1.f + __expf(-x)); }
__device__ __forceinline__ float tanhf_(float x){ return 1.f - 2.f / (1.f + __expf(2.f * x)); }

// ---------------------------------------------------------------------------
// Prepack: transposed (K-major) weight layouts for coalesced streaming.
//   WpreT fp32 [k][r] : rows [cwih | pwhh]  (for the PRE GEMM)
//   WbigT bf16 [k][r] : rows [cwhh | pwih]  (per-step matvec from M)
//   WrcatT bf16 [k][r]: rows [wr0 | wr1 | wk | pad] (production matvec from Hnew)
//   biasPre = [cbih | pbhh], gbias = [cbhh | pbih]
// ---------------------------------------------------------------------------
__global__ void prepack_kernel(
    const float* __restrict__ gat_w, const float* __restrict__ wr0, const float* __restrict__ wr1,
    const float* __restrict__ c_wih, const float* __restrict__ c_whh,
    const float* __restrict__ c_bih, const float* __restrict__ c_bhh,
    const float* __restrict__ p_wih, const float* __restrict__ p_whh,
    const float* __restrict__ p_bih, const float* __restrict__ p_bhh,
    float* __restrict__ WpreT, unsigned short* __restrict__ WbigT,
    unsigned short* __restrict__ WrcatT, float* __restrict__ biasPre, float* __restrict__ gbias)
{
    int idx = blockIdx.x * blockDim.x + threadIdx.x;
    if (idx >= DH_ * G6) return;
    int k = idx / G6, r = idx - k * G6;
    for (int l = 0; l < L_; ++l) {
        const float* cwih = c_wih + l * G3 * DH_;
        const float* cwhh = c_whh + l * G3 * DH_;
        const float* pwih = p_wih + l * G3 * DH_;
        const float* pwhh = p_whh + l * G3 * DH_;
        float wpre = (r < G3) ? cwih[r * DH_ + k] : pwhh[(r - G3) * DH_ + k];
        WpreT[l * DH_ * G6 + k * G6 + r] = wpre;
        float wbig = (r < G3) ? cwhh[r * DH_ + k] : pwih[(r - G3) * DH_ + k];
        WbigT[l * DH_ * G6 + k * G6 + r] = f2bf(wbig);
        if (r < WRC) {
            float v;
            if (r < DH_)            v = wr0[l * DH_ * DH_ + r * DH_ + k];
            else if (r < 2 * DH_)   v = wr1[l * DH_ * DH_ + (r - DH_) * DH_ + k];
            else if (r == 2 * DH_)  v = gat_w[l * 2 * DH_ + DH_ + k];   // wk
            else                    v = 0.f;
            WrcatT[l * DH_ * WRC + k * WRC + r] = f2bf(v);
        }
        if (idx < G6) {  // k==0 thread row handles biases
            biasPre[l * G6 + idx] = (idx < G3) ? c_bih[l * G3 + idx] : p_bhh[l * G3 + idx - G3];
            gbias [l * G6 + idx] = (idx < G3) ? c_bhh[l * G3 + idx] : p_bih[l * G3 + idx - G3];
        }
    }
}

// ---------------------------------------------------------------------------
// Generic small GEMM:  C[r][c] = relu?( sum_k A[r*lda+k] * B[k*cols+c] + bias[c] )
// block = 192 threads (1 col each), 8 rows per block. cols % 192 == 0, K % 64 == 0.
// ---------------------------------------------------------------------------
#define GR 8
__global__ __launch_bounds__(192) void gemm_kernel(
    const float* __restrict__ A, int lda, const float* __restrict__ Bm,
    const float* __restrict__ bias, float* __restrict__ C, int ldc,
    int K, int cols, int relu)
{
    __shared__ float sA[GR][64];
    const int c  = blockIdx.y * 192 + threadIdx.x;
    const int r0 = blockIdx.x * GR;
    float acc[GR] = {0.f, 0.f, 0.f, 0.f, 0.f, 0.f, 0.f, 0.f};
    for (int k0 = 0; k0 < K; k0 += 64) {
        for (int idx = threadIdx.x; idx < GR * 64; idx += 192) {
            int rr = idx >> 6, kk = idx & 63;
            sA[rr][kk] = A[(size_t)(r0 + rr) * lda + k0 + kk];
        }
        __syncthreads();
        #pragma unroll 8
        for (int kk = 0; kk < 64; ++kk) {
            float bv = Bm[(size_t)(k0 + kk) * cols + c];
            #pragma unroll
            for (int rr = 0; rr < GR; ++rr) acc[rr] += sA[rr][kk] * bv;
        }
        __syncthreads();
    }
    float bv = bias[c];
    #pragma unroll
    for (int rr = 0; rr < GR; ++rr) {
        float v = acc[rr] + bv;
        if (relu) v = fmaxf(v, 0.f);
        C[(size_t)(r0 + rr) * ldc + c] = v;
    }
}

// ---------------------------------------------------------------------------
// Sequential scan: one workgroup per batch, 256 steps with __syncthreads.
//   V01 cache (bf16, interleaved v0/v1 per element) lives in global ws;
//   Ksc lives in LDS. gat_b scalar dropped (cancels in softmax).
// ---------------------------------------------------------------------------
__global__ __launch_bounds__(576) void scan_kernel(
    const float* __restrict__ xin,  float* __restrict__ hout,      // slices of Hcat, row stride 576
    const float* __restrict__ PRE,  const float* __restrict__ adj,
    const float* __restrict__ smask,
    const unsigned short* __restrict__ WbigT,
    const unsigned short* __restrict__ WrcatT,
    const float* __restrict__ gbias, const float* __restrict__ wq,
    unsigned short* __restrict__ V01, float* __restrict__ As)
{
    const int b = blockIdx.x;
    const int t = threadIdx.x;
    const int wave = t >> 6, lane = t & 63;
    __shared__ float sKsc[N_];
    __shared__ float sA0[N_], sA1[N_];
    __shared__ float sX[DH_], sM[DH_], sH[DH_];
    __shared__ float sG[G6];                   // matvec out; also M-partials scratch
    __shared__ float sRedX[12], sRedM[12], sRedS[12];

    if (t < N_) sKsc[t] = 0.f;
    const float* adjB = adj   + (size_t)b * N_ * N_;
    const float* smB  = smask + (size_t)b * N_ * N_;
    float* AsB        = As    + (size_t)b * (L_ * N_ * N_);
    unsigned short* Vb = V01  + (size_t)b * N_ * DH_ * 2;
    const int g3 = t / DH_;          // 0..2 for t<576
    const int dd = t - g3 * DH_;     // 0..191
    __syncthreads();

    for (int i = 0; i < N_; ++i) {
        const int row = b * N_ + i;
        // ---- load x_i, compute xq = x_i . wq -------------------------------
        float px = 0.f;
        if (t < DH_) { float v = xin[(size_t)row * G3 + t]; sX[t] = v; px = v * wq[t]; }
        #pragma unroll
        for (int o = 32; o; o >>= 1) px += __shfl_xor(px, o);
        if (lane == 0) sRedX[wave] = px;
        __syncthreads();                                        // (1)
        float xq = 0.f;
        #pragma unroll
        for (int w9 = 0; w9 < 9; ++w9) xq += sRedX[w9];

        // ---- attention ------------------------------------------------------
        if (i == 0) {
            if (t < N_) { sA0[t] = 0.f; sA1[t] = 0.f; AsB[t] = 0.f; }
            if (t < DH_) sM[t] = 0.f;
            __syncthreads();
        } else {
            bool msk = false; float s = -3.4e38f;
            if (t < N_) {
                msk = (t < i) && (adjB[i * N_ + t] > 0.5f);
                if (msk) s = xq + sKsc[t];
            }
            float m = s;
            #pragma unroll
            for (int o = 32; o; o >>= 1) m = fmaxf(m, __shfl_xor(m, o));
            if (lane == 0) sRedM[wave] = m;
            __syncthreads();                                    // (2)
            float mx = -3.4e38f;
            #pragma unroll
            for (int w9 = 0; w9 < 9; ++w9) mx = fmaxf(mx, sRedM[w9]);
            float e = msk ? __expf(s - mx) : 0.f;
            float ps = e;
            #pragma unroll
            for (int o = 32; o; o >>= 1) ps += __shfl_xor(ps, o);
            if (lane == 0) sRedS[wave] = ps;
            __syncthreads();                                    // (3)
            float ssum = 0.f;
            #pragma unroll
            for (int w9 = 0; w9 < 9; ++w9) ssum += sRedS[w9];
            if (t < N_) {
                float a = e / ssum;                 // exact 0 for masked-out
                AsB[i * N_ + t] = a;
                float smv = smB[i * N_ + t];
                float a0 = a * smv;
                sA0[t] = a0; sA1[t] = a - a0;
            }
            __syncthreads();                                    // (4)
            // M_d = sum_{j<i} a0_j*V0[j][d] + a1_j*V1[j][d]   (bf16 V cache)
            float acc = 0.f;
            for (int j = g3; j < i; j += 3) {
                uint32_t w = *(const uint32_t*)(Vb + (((size_t)j * DH_ + dd) << 1));
                acc += sA0[j] * bf2f(w & 0xffffu) + sA1[j] * bf2f(w >> 16);
            }
            sG[g3 * DH_ + dd] = acc;
            __syncthreads();                                    // (5)
            if (t < DH_) sM[t] = sG[t] + sG[DH_ + t] + sG[2 * DH_ + t];
            __syncthreads();                                    // (6)
        }

        // ---- g = M @ [cwhh|pwih]^T  (1152 outs, bf16 stream, pairs) --------
        {
            float a0 = 0.f, a1 = 0.f;
            const unsigned short* Wp = WbigT + 2 * t;
            #pragma unroll 4
            for (int k = 0; k < DH_; ++k) {
                uint32_t w = *(const uint32_t*)(Wp + (size_t)k * G6);
                float mk = sM[k];
                a0 = fmaf(mk, bf2f(w & 0xffffu), a0);
                a1 = fmaf(mk, bf2f(w >> 16),    a1);
            }
            sG[2 * t] = a0; sG[2 * t + 1] = a1;
        }
        __syncthreads();                                        // (7)

        // ---- GRU gates: C = gru(x, M, cw), P = gru(M, x, cp), Hnew = C+P ---
        if (t < DH_) {
            const float* pre = PRE + (size_t)row * G6;
            float Mv = sM[t], xv = sX[t];
            // C-GRU: gi = pre[0:576] (has bih), gh = sG[0:576] + gbias[0:576] (bhh)
            float r1 = sigm(pre[t]        + sG[t]        + gbias[t]);
            float z1 = sigm(pre[DH_ + t]  + sG[DH_ + t]  + gbias[DH_ + t]);
            float n1 = tanhf_(pre[2*DH_+t] + r1 * (sG[2*DH_+t] + gbias[2*DH_+t]));
            float Cv = (1.f - z1) * n1 + z1 * Mv;
            // P-GRU: gi = sG[576:1152] + gbias[576:1152] (bih), gh = pre[576:1152] (has bhh)
            float r2 = sigm(sG[G3 + t]        + gbias[G3 + t]        + pre[G3 + t]);
            float z2 = sigm(sG[G3 + DH_ + t]  + gbias[G3 + DH_ + t]  + pre[G3 + DH_ + t]);
            float n2 = tanhf_(sG[G3 + 2*DH_ + t] + gbias[G3 + 2*DH_ + t] + r2 * pre[G3 + 2*DH_ + t]);
            float Pv = (1.f - z2) * n2 + z2 * xv;
            float Hn = Cv + Pv;
            sH[t] = Hn;
            hout[(size_t)row * G3 + t] = Hn;
        }
        __syncthreads();                                        // (8)

        // ---- production: [V0_i | V1_i | Ksc_i] = Hnew @ [wr0|wr1|wk]^T -----
        if (t < 224) {
            float a0 = 0.f, a1 = 0.f;
            const unsigned short* Wp = WrcatT + 2 * t;
            #pragma unroll 4
            for (int k = 0; k < DH_; ++k) {
                uint32_t w = *(const uint32_t*)(Wp + (size_t)k * WRC);
                float hk = sH[k];
                a0 = fmaf(hk, bf2f(w & 0xffffu), a0);
                a1 = fmaf(hk, bf2f(w >> 16),    a1);
            }
            int r0 = 2 * t, r1i = 2 * t + 1;
            if (r0 < DH_)            Vb[(((size_t)i * DH_ + r0) << 1)]            = f2bf(a0);
            else if (r0 < 2 * DH_)   Vb[(((size_t)i * DH_ + r0 - DH_) << 1) + 1]  = f2bf(a0);
            else if (r0 == 2 * DH_)  sKsc[i] = a0;
            if (r1i < DH_)           Vb[(((size_t)i * DH_ + r1i) << 1)]           = f2bf(a1);
            else if (r1i < 2 * DH_)  Vb[(((size_t)i * DH_ + r1i - DH_) << 1) + 1] = f2bf(a1);
            else if (r1i == 2 * DH_) sKsc[i] = a1;
        }
        __syncthreads();                                        // (9)
    }
}

// ---------------------------------------------------------------------------
extern "C" void kernel_launch(void* const* d_in, const int* in_sizes, int n_in,
                              void* d_out, int out_size, void* d_ws, size_t ws_size,
                              hipStream_t stream)
{
    const float* features = (const float*)d_in[0];
    const float* adj      = (const float*)d_in[1];
    const float* smask    = (const float*)d_in[2];
    // d_in[3] s_mask_onehot, d_in[4] lengths: unused by reference math
    const float* fc1_w = (const float*)d_in[5];
    const float* fc1_b = (const float*)d_in[6];
    const float* gat_w = (const float*)d_in[7];
    // d_in[8] gat_b: scalar per layer, cancels in softmax
    const float* wr0   = (const float*)d_in[9];
    const float* wr1   = (const float*)d_in[10];
    const float* c_wih = (const float*)d_in[11];
    const float* c_whh = (const float*)d_in[12];
    const float* c_bih = (const float*)d_in[13];
    const float* c_bhh = (const float*)d_in[14];
    const float* p_wih = (const float*)d_in[15];
    const float* p_whh = (const float*)d_in[16];
    const float* p_bih = (const float*)d_in[17];
    const float* p_bhh = (const float*)d_in[18];
    const float* mw0 = (const float*)d_in[19];
    const float* mb0 = (const float*)d_in[20];
    const float* mw1 = (const float*)d_in[21];
    const float* mb1 = (const float*)d_in[22];
    const float* mw2 = (const float*)d_in[23];
    const float* mb2 = (const float*)d_in[24];
    float* out = (float*)d_out;

    char* wsb = (char*)d_ws;
    size_t off = 0;
    auto carve = [&](size_t bytes) -> char* {
        char* p = wsb + off;
        off = (off + bytes + 255) & ~(size_t)255;
        return p;
    };
    float* Hcat            = (float*)carve(2048ull * 576 * 4);   // [H0|H1|H2] per row
    float* PRE             = (float*)carve(2048ull * 1152 * 4);  // reused as h1/h2 after scans
    float* WpreT           = (float*)carve(2ull * 192 * 1152 * 4);
    float* biasPre         = (float*)carve(2ull * 1152 * 4);
    float* gbias           = (float*)carve(2ull * 1152 * 4);
    unsigned short* WbigT  = (unsigned short*)carve(2ull * 192 * 1152 * 2);
    unsigned short* WrcatT = (unsigned short*)carve(2ull * 192 * WRC * 2);
    unsigned short* V01    = (unsigned short*)carve(8ull * 256 * 192 * 2 * 2);
    float* h1 = PRE;
    float* h2 = PRE + 2048 * 192;

    prepack_kernel<<<dim3((192 * 1152 + 255) / 256), 256, 0, stream>>>(
        gat_w, wr0, wr1, c_wih, c_whh, c_bih, c_bhh, p_wih, p_whh, p_bih, p_bhh,
        WpreT, WbigT, WrcatT, biasPre, gbias);

    // Hl0 = relu(features @ fc1_w + fc1_b) -> Hcat slice 0
    gemm_kernel<<<dim3(256, 1), 192, 0, stream>>>(features, 768, fc1_w, fc1_b,
                                                  Hcat, 576, 768, 192, 1);
    for (int l = 0; l < 2; ++l) {
        // PRE = x @ [cwih|pwhh]^T + [cbih|pbhh]
        gemm_kernel<<<dim3(256, 6), 192, 0, stream>>>(Hcat + l * 192, 576,
            WpreT + (size_t)l * 192 * 1152, biasPre + l * 1152, PRE, 1152, 192, 1152, 0);
        scan_kernel<<<dim3(8), 576, 0, stream>>>(Hcat + l * 192, Hcat + (l + 1) * 192,
            PRE, adj, smask, WbigT + (size_t)l * 192 * 1152, WrcatT + (size_t)l * 192 * WRC,
            gbias + l * 1152, gat_w + l * 384, V01,
            out + 393216 + l * 65536);
    }
    // MLP head
    gemm_kernel<<<dim3(256, 1), 192, 0, stream>>>(Hcat, 576, mw0, mb0, h1, 192, 576, 192, 1);
    gemm_kernel<<<dim3(256, 1), 192, 0, stream>>>(h1, 192, mw1, mb1, h2, 192, 192, 192, 1);
    gemm_kernel<<<dim3(256, 1), 192, 0, stream>>>(h2, 192, mw2, mb2, out, 192, 192, 192, 0);
}